// Round 10
// baseline (2244.273 us; speedup 1.0000x reference)
//
#include <hip/hip_runtime.h>
#include <hip/hip_bf16.h>
#include <math.h>

typedef unsigned short u16;
typedef unsigned long long u64;
typedef __attribute__((ext_vector_type(8))) short short8;
typedef __attribute__((ext_vector_type(4))) short short4v;
typedef __attribute__((ext_vector_type(4))) float floatx4;

__device__ __forceinline__ float bf2f(u16 u) {
  union { float f; unsigned u; } v; v.u = ((unsigned)u) << 16; return v.f;
}
__device__ __forceinline__ u16 f2bf(float f) {
  union { float f; unsigned u; } v; v.f = f;
  unsigned r = (v.u + 0x7FFFu + ((v.u >> 16) & 1u)) >> 16;
  return (u16)r;
}
__device__ __forceinline__ float sigm(float x) {
  return __builtin_amdgcn_rcpf(1.0f + __expf(-x));
}
__device__ __forceinline__ float ftanh(float x) {
  return 1.0f - 2.0f * __builtin_amdgcn_rcpf(1.0f + __expf(2.0f * x));
}

// async global->LDS, 16B/lane; LDS dest = wave-uniform base + lane*16
__device__ __forceinline__ void ld_g2l16(const u16* g, u16* l) {
  __builtin_amdgcn_global_load_lds(
      (const __attribute__((address_space(1))) void*)g,
      (__attribute__((address_space(3))) void*)l, 16, 0, 0);
}

// R4/R7-measured-best grid order: per XCD, by fastest within a disjoint strip.
__device__ __forceinline__ void swz(int blk, int NX, int NY, int& bx, int& by) {
  if ((NY & 7) == 0) {
    const int strip = NY >> 3;
    const int xcd = blk & 7;
    const int q = blk >> 3;
    bx = q / strip;
    by = xcd * strip + (q - bx * strip);
  } else {
    bx = blk % NX;
    by = blk / NX;
  }
}

#define BM 128
#define BN 128
#define BK 64    // 32 K-iters at K=2048: fewest barrier drains (R5-vs-R6 measured win)
                 // LDS row = 128B = 8x16B chunks; XOR chunk^(row&7) -> conflict-free (R5: 0)

#define MODE_ZR   1
#define MODE_OUT  2

// ---------------- token gather + f32->bf16 convert (streaming)
__global__ __launch_bounds__(256) void gather_word(
    const int* __restrict__ tokens, const float* __restrict__ emb,
    u16* __restrict__ word)   // 32768 x 512 bf16
{
  const int t = blockIdx.x * 256 + threadIdx.x;
  const int row = t >> 6;
  const int col = (t & 63) * 8;
  const float* src = emb + (size_t)tokens[row] * 512 + col;
  float4 a = *(const float4*)src;
  float4 b = *(const float4*)(src + 4);
  short8 v;
  v[0] = (short)f2bf(a.x); v[1] = (short)f2bf(a.y);
  v[2] = (short)f2bf(a.z); v[3] = (short)f2bf(a.w);
  v[4] = (short)f2bf(b.x); v[5] = (short)f2bf(b.y);
  v[6] = (short)f2bf(b.z); v[7] = (short)f2bf(b.w);
  *(short8*)(word + (size_t)row * 512 + col) = v;
}

// ---------------- Leaf: h = (1 - sigm(word@Wz + bz)) * tanh(word@Wh + bh)
__global__ __launch_bounds__(256) void leaf_fused(
    const u16* __restrict__ word, const u16* __restrict__ BLT,
    const float* __restrict__ bz, const float* __restrict__ bh,
    u16* __restrict__ hout)   // 32768 x 1024 bf16
{
  __shared__ u16 sA [BM * BK];
  __shared__ u16 sBz[BN * BK];
  __shared__ u16 sBh[BN * BK];
  const int tid  = threadIdx.x;
  int bx, by; swz(blockIdx.x, 8, 256, bx, by);
  const int m0   = by * BM;
  const int n0   = bx * BN;
  const int lane = tid & 63;
  const int wave = tid >> 6;
  const int wm   = (wave >> 1) * 64;
  const int wn   = (wave & 1) * 64;
  const int lr   = lane & 15;
  const int q4   = lane >> 4;
  const int qd   = q4 * 4;
  const int xs   = lr & 7;
  const int srow = lane >> 3;
  const int sc   = lane & 7;
  const int goff = (sc ^ srow) * 8;

  const u16* aP [4]; const u16* bzP[4]; const u16* bhP[4];
  #pragma unroll
  for (int t = 0; t < 4; ++t) {
    const int row = (wave * 4 + t) * 8 + srow;
    aP [t] = word + (size_t)(m0 + row) * 512 + goff;
    bzP[t] = BLT  + (size_t)(n0 + row) * 512 + goff;
    bhP[t] = BLT  + (size_t)(1024 + n0 + row) * 512 + goff;
  }

  floatx4 accz[4][4], acch[4][4];
  #pragma unroll
  for (int j = 0; j < 4; ++j)
    #pragma unroll
    for (int i = 0; i < 4; ++i) {
      accz[j][i] = (floatx4){0.f, 0.f, 0.f, 0.f};
      acch[j][i] = (floatx4){0.f, 0.f, 0.f, 0.f};
    }

  for (int kt = 0; kt < 512 / BK; ++kt) {
    #pragma unroll
    for (int t = 0; t < 4; ++t) {
      const int slab = wave * 4 + t;
      ld_g2l16(aP [t], &sA [slab * 512]);
      ld_g2l16(bzP[t], &sBz[slab * 512]);
      ld_g2l16(bhP[t], &sBh[slab * 512]);
      aP[t] += BK; bzP[t] += BK; bhP[t] += BK;
    }
    __syncthreads();
    #pragma unroll
    for (int s = 0; s < 2; ++s) {
      const int ck = ((s * 4 + q4) ^ xs) * 8;
      short8 af[4], bz8[4], bh8[4];
      #pragma unroll
      for (int i = 0; i < 4; ++i)
        af[i] = *(const short8*)(&sA[(wm + i * 16 + lr) * BK + ck]);
      #pragma unroll
      for (int j = 0; j < 4; ++j) {
        bz8[j] = *(const short8*)(&sBz[(wn + j * 16 + lr) * BK + ck]);
        bh8[j] = *(const short8*)(&sBh[(wn + j * 16 + lr) * BK + ck]);
      }
      #pragma unroll
      for (int j = 0; j < 4; ++j)
        #pragma unroll
        for (int i = 0; i < 4; ++i) {
          accz[j][i] = __builtin_amdgcn_mfma_f32_16x16x32_bf16(bz8[j], af[i], accz[j][i], 0, 0, 0);
          acch[j][i] = __builtin_amdgcn_mfma_f32_16x16x32_bf16(bh8[j], af[i], acch[j][i], 0, 0, 0);
        }
    }
    __syncthreads();
  }

  #pragma unroll
  for (int j = 0; j < 4; ++j) {
    const int cb = n0 + wn + j * 16 + qd;
    const float4 bz4 = *(const float4*)(bz + cb);
    const float4 bh4 = *(const float4*)(bh + cb);
    #pragma unroll
    for (int i = 0; i < 4; ++i) {
      const int grow = m0 + wm + i * 16 + lr;
      short4v o;
      #pragma unroll
      for (int r = 0; r < 4; ++r) {
        const float z  = sigm(accz[j][i][r] + ((const float*)&bz4)[r]);
        const float ht = ftanh(acch[j][i][r] + ((const float*)&bh4)[r]);
        o[r] = (short)f2bf((1.f - z) * ht);
      }
      *(short4v*)(hout + (size_t)grow * 1024 + cb) = o;
    }
  }
}

// ---------------- Big-level GEMM (levels 0-2): C = A @ BT^T, fused epilogues.
__global__ __launch_bounds__(256) void gemm_fused(
    const u16* __restrict__ A, const u16* __restrict__ BT,
    int M, int K, int NX, int NY, int mode,
    const float* __restrict__ bias_z, const float* __restrict__ bias_r,
    const float* __restrict__ bias_h,
    const u16* __restrict__ hin2, const u16* __restrict__ zin,
    u16* __restrict__ out0, u16* __restrict__ out1, float* __restrict__ outf)
{
  __shared__ u16 sA[BM * BK];
  __shared__ u16 sB[BN * BK];
  const int tid  = threadIdx.x;
  int bx, by; swz(blockIdx.x, NX, NY, bx, by);
  const int m0   = by * BM;
  const int n0   = bx * BN;
  const int lane = tid & 63;
  const int wave = tid >> 6;
  const int wm   = (wave >> 1) * 64;
  const int wn   = (wave & 1) * 64;
  const int lr   = lane & 15;
  const int q4   = lane >> 4;
  const int qd   = q4 * 4;
  const int xs   = lr & 7;
  const int srow = lane >> 3;
  const int sc   = lane & 7;
  const int goff = (sc ^ srow) * 8;

  const u16* aP[4]; const u16* bP[4];
  #pragma unroll
  for (int t = 0; t < 4; ++t) {
    const int row = (wave * 4 + t) * 8 + srow;
    aP[t] = A  + (size_t)(m0 + row) * K + goff;
    bP[t] = BT + (size_t)(n0 + row) * K + goff;
  }

  floatx4 acc[4][4];
  #pragma unroll
  for (int j = 0; j < 4; ++j)
    #pragma unroll
    for (int i = 0; i < 4; ++i)
      acc[j][i] = (floatx4){0.f, 0.f, 0.f, 0.f};

  const int ksteps = K / BK;
  for (int kt = 0; kt < ksteps; ++kt) {
    #pragma unroll
    for (int t = 0; t < 4; ++t) {
      const int slab = wave * 4 + t;
      ld_g2l16(aP[t], &sA[slab * 512]);
      ld_g2l16(bP[t], &sB[slab * 512]);
      aP[t] += BK; bP[t] += BK;
    }
    __syncthreads();
    #pragma unroll
    for (int s = 0; s < 2; ++s) {
      const int ck = ((s * 4 + q4) ^ xs) * 8;
      short8 af[4], bfr[4];
      #pragma unroll
      for (int i = 0; i < 4; ++i)
        af[i] = *(const short8*)(&sA[(wm + i * 16 + lr) * BK + ck]);
      #pragma unroll
      for (int j = 0; j < 4; ++j)
        bfr[j] = *(const short8*)(&sB[(wn + j * 16 + lr) * BK + ck]);
      #pragma unroll
      for (int j = 0; j < 4; ++j)
        #pragma unroll
        for (int i = 0; i < 4; ++i)
          acc[j][i] = __builtin_amdgcn_mfma_f32_16x16x32_bf16(bfr[j], af[i], acc[j][i], 0, 0, 0);
    }
    __syncthreads();
  }

  #pragma unroll
  for (int j = 0; j < 4; ++j) {
    const int cb = n0 + wn + j * 16 + qd;
    if (mode == MODE_ZR) {
      if (cb < 1024) {
        const float4 b4 = *(const float4*)(bias_z + cb);
        #pragma unroll
        for (int i = 0; i < 4; ++i) {
          const int grow = m0 + wm + i * 16 + lr;
          if (grow >= M) continue;
          short4v o;
          #pragma unroll
          for (int r = 0; r < 4; ++r)
            o[r] = (short)f2bf(sigm(acc[j][i][r] + ((const float*)&b4)[r]));
          *(short4v*)(out0 + (size_t)grow * 1024 + cb) = o;
        }
      } else {
        const int c2 = cb - 1024;
        const float4 b4 = *(const float4*)(bias_r + c2);
        #pragma unroll
        for (int i = 0; i < 4; ++i) {
          const int grow = m0 + wm + i * 16 + lr;
          if (grow >= M) continue;
          const short4v hl4 = *(const short4v*)(hin2 + (size_t)grow * 2048 + c2);
          const short4v hr4 = *(const short4v*)(hin2 + (size_t)grow * 2048 + 1024 + c2);
          short4v ol, orr;
          #pragma unroll
          for (int r = 0; r < 4; ++r) {
            const float rv = sigm(acc[j][i][r] + ((const float*)&b4)[r]);
            ol[r]  = (short)f2bf(rv * bf2f((u16)hl4[r]));
            orr[r] = (short)f2bf(rv * bf2f((u16)hr4[r]));
          }
          *(short4v*)(out1 + (size_t)grow * 2048 + c2)        = ol;
          *(short4v*)(out1 + (size_t)grow * 2048 + 1024 + c2) = orr;
        }
      }
    } else { // MODE_OUT
      const float4 b4 = *(const float4*)(bias_h + cb);
      #pragma unroll
      for (int i = 0; i < 4; ++i) {
        const int grow = m0 + wm + i * 16 + lr;
        if (grow >= M) continue;
        const short4v z4  = *(const short4v*)(zin  + (size_t)grow * 1024 + cb);
        const short4v hl4 = *(const short4v*)(hin2 + (size_t)grow * 2048 + cb);
        const short4v hr4 = *(const short4v*)(hin2 + (size_t)grow * 2048 + 1024 + cb);
        float h[4];
        #pragma unroll
        for (int r = 0; r < 4; ++r) {
          const float ht = ftanh(acc[j][i][r] + ((const float*)&b4)[r]);
          const float z  = bf2f((u16)z4[r]);
          h[r] = z * (bf2f((u16)hl4[r]) + bf2f((u16)hr4[r])) + (1.f - z) * ht;
        }
        if (outf) {
          *(float4*)(outf + (size_t)grow * 1024 + cb) = (float4){h[0], h[1], h[2], h[3]};
        } else {
          short4v o;
          #pragma unroll
          for (int r = 0; r < 4; ++r) o[r] = (short)f2bf(h[r]);
          *(short4v*)(out0 + (size_t)grow * 1024 + cb) = o;
        }
      }
    }
  }
}

// ---------------- Fused election split-K (levels 3-8), single dispatch/stage.
// bf16 partial stores (plain), 1 counter atomic/block; last block per tile sums
// other slices via agent-scope loads (+ own regs), applies epilogue, zeros cnt.
__global__ __launch_bounds__(256) void gemm_spk(
    const u16* __restrict__ A, const u16* __restrict__ BT,
    int M, int K, int TX, int S, int mode,
    const float* __restrict__ bias_z, const float* __restrict__ bias_r,
    const float* __restrict__ bias_h,
    const u16* __restrict__ hin2, const u16* __restrict__ zin,
    u16* __restrict__ out0, u16* __restrict__ out1, float* __restrict__ outf,
    u16* __restrict__ pbuf, int* __restrict__ cnt)
{
  __shared__ u16 sA[BM * BK];
  __shared__ u16 sB[BN * BK];
  __shared__ int sLast;
  const int tid  = threadIdx.x;
  const int blk  = blockIdx.x;
  const int sp   = blk % S;
  const int tile = blk / S;
  const int bx   = tile % TX;
  const int by   = tile / TX;
  const int N    = TX * 128;
  const int Mr   = (gridDim.x / (TX * S)) * 128;
  const int m0   = by * BM;
  const int n0   = bx * BN;
  const int k0   = sp * (K / S);
  const int lane = tid & 63;
  const int wave = tid >> 6;
  const int wm   = (wave >> 1) * 64;
  const int wn   = (wave & 1) * 64;
  const int lr   = lane & 15;
  const int q4   = lane >> 4;
  const int qd   = q4 * 4;
  const int xs   = lr & 7;
  const int srow = lane >> 3;
  const int sc   = lane & 7;
  const int goff = (sc ^ srow) * 8;

  const u16* aP[4]; const u16* bP[4];
  #pragma unroll
  for (int t = 0; t < 4; ++t) {
    const int row = (wave * 4 + t) * 8 + srow;
    aP[t] = A  + (size_t)(m0 + row) * K + k0 + goff;  // OOB rows: in-ws garbage, masked at output
    bP[t] = BT + (size_t)(n0 + row) * K + k0 + goff;
  }

  floatx4 acc[4][4];
  #pragma unroll
  for (int j = 0; j < 4; ++j)
    #pragma unroll
    for (int i = 0; i < 4; ++i)
      acc[j][i] = (floatx4){0.f, 0.f, 0.f, 0.f};

  const int ksteps = (K / S) / BK;
  for (int kt = 0; kt < ksteps; ++kt) {
    #pragma unroll
    for (int t = 0; t < 4; ++t) {
      const int slab = wave * 4 + t;
      ld_g2l16(aP[t], &sA[slab * 512]);
      ld_g2l16(bP[t], &sB[slab * 512]);
      aP[t] += BK; bP[t] += BK;
    }
    __syncthreads();
    #pragma unroll
    for (int s = 0; s < 2; ++s) {
      const int ck = ((s * 4 + q4) ^ xs) * 8;
      short8 af[4], bfr[4];
      #pragma unroll
      for (int i = 0; i < 4; ++i)
        af[i] = *(const short8*)(&sA[(wm + i * 16 + lr) * BK + ck]);
      #pragma unroll
      for (int j = 0; j < 4; ++j)
        bfr[j] = *(const short8*)(&sB[(wn + j * 16 + lr) * BK + ck]);
      #pragma unroll
      for (int j = 0; j < 4; ++j)
        #pragma unroll
        for (int i = 0; i < 4; ++i)
          acc[j][i] = __builtin_amdgcn_mfma_f32_16x16x32_bf16(bfr[j], af[i], acc[j][i], 0, 0, 0);
    }
    __syncthreads();
  }

  // store own partial slice as bf16 (plain stores)
  u16* base = pbuf + (size_t)sp * Mr * N;
  #pragma unroll
  for (int j = 0; j < 4; ++j) {
    const int cb = n0 + wn + j * 16 + qd;
    #pragma unroll
    for (int i = 0; i < 4; ++i) {
      const int grow = m0 + wm + i * 16 + lr;
      short4v o;
      #pragma unroll
      for (int r = 0; r < 4; ++r) o[r] = (short)f2bf(acc[j][i][r]);
      *(short4v*)(base + (size_t)grow * N + cb) = o;
    }
  }
  __syncthreads();                 // drains all waves' stores (vmcnt(0) before barrier)
  if (tid == 0) {
    __threadfence();               // release: partials visible device-wide
    sLast = (atomicAdd(&cnt[tile], 1) == S - 1);
  }
  __syncthreads();
  if (!sLast) return;
  __threadfence();                 // acquire side

  // elected: sum other slices (agent-scope coherent loads) + own regs, epilogue
  #pragma unroll
  for (int j = 0; j < 4; ++j) {
    const int cb = n0 + wn + j * 16 + qd;
    #pragma unroll
    for (int i = 0; i < 4; ++i) {
      const int grow = m0 + wm + i * 16 + lr;
      float v[4] = {acc[j][i][0], acc[j][i][1], acc[j][i][2], acc[j][i][3]};
      for (int s = 0; s < S; ++s) {
        if (s == sp) continue;
        const u16* sl = pbuf + ((size_t)s * Mr + grow) * N + cb;
        const u64 w = __hip_atomic_load((const u64*)sl, __ATOMIC_RELAXED,
                                        __HIP_MEMORY_SCOPE_AGENT);
        v[0] += bf2f((u16)(w));
        v[1] += bf2f((u16)(w >> 16));
        v[2] += bf2f((u16)(w >> 32));
        v[3] += bf2f((u16)(w >> 48));
      }
      if (grow < M) {
        if (mode == MODE_ZR) {
          if (cb < 1024) {
            short4v o;
            #pragma unroll
            for (int r = 0; r < 4; ++r)
              o[r] = (short)f2bf(sigm(v[r] + bias_z[cb + r]));
            *(short4v*)(out0 + (size_t)grow * 1024 + cb) = o;
          } else {
            const int c2 = cb - 1024;
            const short4v hl4 = *(const short4v*)(hin2 + (size_t)grow * 2048 + c2);
            const short4v hr4 = *(const short4v*)(hin2 + (size_t)grow * 2048 + 1024 + c2);
            short4v ol, orr;
            #pragma unroll
            for (int r = 0; r < 4; ++r) {
              const float rv = sigm(v[r] + bias_r[c2 + r]);
              ol[r]  = (short)f2bf(rv * bf2f((u16)hl4[r]));
              orr[r] = (short)f2bf(rv * bf2f((u16)hr4[r]));
            }
            *(short4v*)(out1 + (size_t)grow * 2048 + c2)        = ol;
            *(short4v*)(out1 + (size_t)grow * 2048 + 1024 + c2) = orr;
          }
        } else { // MODE_OUT
          const short4v z4  = *(const short4v*)(zin  + (size_t)grow * 1024 + cb);
          const short4v hl4 = *(const short4v*)(hin2 + (size_t)grow * 2048 + cb);
          const short4v hr4 = *(const short4v*)(hin2 + (size_t)grow * 2048 + 1024 + cb);
          float h[4];
          #pragma unroll
          for (int r = 0; r < 4; ++r) {
            const float ht = ftanh(v[r] + bias_h[cb + r]);
            const float z  = bf2f((u16)z4[r]);
            h[r] = z * (bf2f((u16)hl4[r]) + bf2f((u16)hr4[r])) + (1.f - z) * ht;
          }
          if (outf) {
            *(float4*)(outf + (size_t)grow * 1024 + cb) = (float4){h[0], h[1], h[2], h[3]};
          } else {
            short4v o;
            #pragma unroll
            for (int r = 0; r < 4; ++r) o[r] = (short)f2bf(h[r]);
            *(short4v*)(out0 + (size_t)grow * 1024 + cb) = o;
          }
        }
      }
    }
  }
  if (tid == 0) cnt[tile] = 0;     // self-reset; visible at next dispatch boundary
}

// ---------------- fused weight/bias packing + cnt zeroing, 1 dispatch
__global__ __launch_bounds__(256) void pack_all(
    const float* __restrict__ Uzl, const float* __restrict__ Uzr,
    const float* __restrict__ Url, const float* __restrict__ Urr,
    const float* __restrict__ Uhl, const float* __restrict__ Uhr,
    const float* __restrict__ Wz,  const float* __restrict__ Wh,
    const float* bz0, const float* bz1, const float* bz2,
    const float* br0, const float* br1, const float* br2,
    const float* bh0, const float* bh1, const float* bh2,
    u16* __restrict__ B1T, u16* __restrict__ B2T, u16* __restrict__ BLT,
    float* __restrict__ bz, float* __restrict__ br, float* __restrict__ bh,
    int* __restrict__ cnt)
{
  int t = blockIdx.x * 256 + threadIdx.x;
  if (t < 2048 * 2048) {                       // B1T
    const int n = t >> 11, k = t & 2047;
    const float* src = (n < 1024) ? ((k < 1024) ? Uzl : Uzr)
                                  : ((k < 1024) ? Url : Urr);
    B1T[t] = f2bf(src[(size_t)(k & 1023) * 1024 + (n & 1023)]);
    return;
  }
  t -= 2048 * 2048;
  if (t < 1024 * 2048) {                       // B2T
    const int n = t >> 11, k = t & 2047;
    const float* src = (k < 1024) ? Uhl : Uhr;
    B2T[t] = f2bf(src[(size_t)(k & 1023) * 1024 + n]);
    return;
  }
  t -= 1024 * 2048;
  if (t < 2048 * 512) {                        // BLT
    const int n = t >> 9, k = t & 511;
    const float* src = (n < 1024) ? Wz : Wh;
    BLT[t] = f2bf(src[(size_t)k * 1024 + (n & 1023)]);
    return;
  }
  t -= 2048 * 512;
  if (t < 1024) {                              // biases
    bz[t] = bz0[t] + bz1[t] + bz2[t];
    br[t] = br0[t] + br1[t] + br2[t];
    bh[t] = bh0[t] + bh1[t] + bh2[t];
    return;
  }
  t -= 1024;
  if (t < 256) cnt[t] = 0;                     // election counters
}

extern "C" void kernel_launch(void* const* d_in, const int* in_sizes, int n_in,
                              void* d_out, int out_size, void* d_ws, size_t ws_size,
                              hipStream_t stream)
{
  const int*   tokens = (const int*)d_in[0];
  const float* emb  = (const float*)d_in[1];
  const float* W_z  = (const float*)d_in[2];
  const float* b_z  = (const float*)d_in[3];
  const float* U_zl = (const float*)d_in[4];
  const float* b_zl = (const float*)d_in[5];
  const float* U_zr = (const float*)d_in[6];
  const float* b_zr = (const float*)d_in[7];
  // d_in[8] = W_r: provably unused (leaf r multiplies zero state)
  const float* b_r  = (const float*)d_in[9];
  const float* U_rl = (const float*)d_in[10];
  const float* b_rl = (const float*)d_in[11];
  const float* U_rr = (const float*)d_in[12];
  const float* b_rr = (const float*)d_in[13];
  const float* W_h  = (const float*)d_in[14];
  const float* b_h  = (const float*)d_in[15];
  const float* U_hl = (const float*)d_in[16];
  const float* b_hl = (const float*)d_in[17];
  const float* U_hr = (const float*)d_in[18];
  const float* b_hr = (const float*)d_in[19];

  char* ws = (char*)d_ws;
  size_t off = 0;
  auto alloc = [&](size_t bytes) -> char* {
    char* p = ws + off; off += (bytes + 255) & ~(size_t)255; return p;
  };
  u16*   B1T  = (u16*)alloc((size_t)2048 * 2048 * 2);   //  8 MB
  u16*   B2T  = (u16*)alloc((size_t)1024 * 2048 * 2);   //  4 MB
  u16*   BLT  = (u16*)alloc((size_t)2048 * 512 * 2);    //  2 MB
  float* bz   = (float*)alloc(1024 * 4);
  float* br   = (float*)alloc(1024 * 4);
  float* bh   = (float*)alloc(1024 * 4);
  int*   cnt  = (int*)alloc(256 * 4);
  u16*   wrd  = (u16*)alloc((size_t)32768 * 512 * 2);   // 32 MB (dead after leaf -> pbuf)
  u16*   hA   = (u16*)alloc((size_t)32768 * 1024 * 2);  // 64 MB
  u16*   hB   = (u16*)alloc((size_t)16384 * 1024 * 2);  // 32 MB
  u16*   zbuf = (u16*)alloc((size_t)16384 * 1024 * 2);  // 32 MB
  u16*   rlrr = (u16*)alloc((size_t)16384 * 2048 * 2);  // 64 MB
  u16*   pbuf = wrd;                                    // aliases wrd (max 32 MB)
  (void)ws_size; (void)in_sizes; (void)n_in; (void)out_size;

  pack_all<<<dim3((2048*2048 + 1024*2048 + 2048*512 + 1024 + 256 + 255) / 256),
             dim3(256), 0, stream>>>(
      U_zl, U_zr, U_rl, U_rr, U_hl, U_hr, W_z, W_h,
      b_z, b_zl, b_zr, b_r, b_rl, b_rr, b_h, b_hl, b_hr,
      B1T, B2T, BLT, bz, br, bh, cnt);

  gather_word<<<dim3(8192), dim3(256), 0, stream>>>(tokens, emb, wrd);
  leaf_fused<<<dim3(8 * 256), dim3(256), 0, stream>>>(wrd, BLT, bz, bh, hA);

  // 9 halving levels; h (2R x 1024) viewed as (R x 2048) = [hl|hr]
  const u16* hin = hA;
  u16* hout = hB;
  int nodes = 32768;
  for (int lvl = 0; lvl < 9; ++lvl) {
    const int R = nodes >> 1;
    float* outf = (lvl == 8) ? (float*)d_out : nullptr;
    if (lvl < 3) {
      const int NY = (R + 127) / 128;
      gemm_fused<<<dim3(16 * NY), dim3(256), 0, stream>>>(
          hin, B1T, R, 2048, 16, NY, MODE_ZR,
          bz, br, bh, hin, nullptr, zbuf, rlrr, nullptr);
      gemm_fused<<<dim3(8 * NY), dim3(256), 0, stream>>>(
          rlrr, B2T, R, 2048, 8, NY, MODE_OUT,
          bz, br, bh, hin, zbuf, hout, nullptr, outf);
    } else {
      const int TY = (R + 127) / 128;
      const int S  = (R >= 1024) ? 4 : (R >= 256) ? 8 : 16;
      // pbuf (bf16) = S*Mr*2048*2 <= 32 MB for all tail levels
      gemm_spk<<<dim3(16 * TY * S), dim3(256), 0, stream>>>(
          hin, B1T, R, 2048, 16, S, MODE_ZR,
          bz, br, bh, hin, nullptr, zbuf, rlrr, nullptr, pbuf, cnt);
      gemm_spk<<<dim3(8 * TY * S), dim3(256), 0, stream>>>(
          rlrr, B2T, R, 2048, 8, S, MODE_OUT,
          bz, br, bh, hin, zbuf, hout, nullptr, outf, pbuf, cnt);
    }
    u16* tmp = (u16*)hin; hin = hout; hout = tmp;
    nodes = R;
  }
}

// Round 11
// 1198.121 us; speedup vs baseline: 1.8732x; 1.8732x over previous
//
#include <hip/hip_runtime.h>
#include <hip/hip_bf16.h>
#include <math.h>

typedef unsigned short u16;
typedef __attribute__((ext_vector_type(8))) short short8;
typedef __attribute__((ext_vector_type(4))) short short4v;
typedef __attribute__((ext_vector_type(4))) float floatx4;

__device__ __forceinline__ float bf2f(u16 u) {
  union { float f; unsigned u; } v; v.u = ((unsigned)u) << 16; return v.f;
}
__device__ __forceinline__ u16 f2bf(float f) {
  union { float f; unsigned u; } v; v.f = f;
  unsigned r = (v.u + 0x7FFFu + ((v.u >> 16) & 1u)) >> 16;
  return (u16)r;
}
__device__ __forceinline__ float sigm(float x) {
  return __builtin_amdgcn_rcpf(1.0f + __expf(-x));
}
__device__ __forceinline__ float ftanh(float x) {
  return 1.0f - 2.0f * __builtin_amdgcn_rcpf(1.0f + __expf(2.0f * x));
}

// async global->LDS, 16B/lane; LDS dest = wave-uniform base + lane*16
__device__ __forceinline__ void ld_g2l16(const u16* g, u16* l) {
  __builtin_amdgcn_global_load_lds(
      (const __attribute__((address_space(1))) void*)g,
      (__attribute__((address_space(3))) void*)l, 16, 0, 0);
}

// R4/R7-measured-best grid order: per XCD, by fastest within a disjoint strip.
__device__ __forceinline__ void swz(int blk, int NX, int NY, int& bx, int& by) {
  if ((NY & 7) == 0) {
    const int strip = NY >> 3;
    const int xcd = blk & 7;
    const int q = blk >> 3;
    bx = q / strip;
    by = xcd * strip + (q - bx * strip);
  } else {
    bx = blk % NX;
    by = blk / NX;
  }
}

#define BM 128
#define BN 128
#define BK 64    // 32 K-iters at K=2048: fewest barrier drains (R5-vs-R6 measured win)
                 // LDS row = 128B = 8x16B chunks; XOR chunk^(row&7) -> conflict-free (R5: 0)

#define MODE_ZR   1
#define MODE_OUT  2

// ---------------- token gather + f32->bf16 convert (streaming)
__global__ __launch_bounds__(256) void gather_word(
    const int* __restrict__ tokens, const float* __restrict__ emb,
    u16* __restrict__ word)   // 32768 x 512 bf16
{
  const int t = blockIdx.x * 256 + threadIdx.x;
  const int row = t >> 6;
  const int col = (t & 63) * 8;
  const float* src = emb + (size_t)tokens[row] * 512 + col;
  float4 a = *(const float4*)src;
  float4 b = *(const float4*)(src + 4);
  short8 v;
  v[0] = (short)f2bf(a.x); v[1] = (short)f2bf(a.y);
  v[2] = (short)f2bf(a.z); v[3] = (short)f2bf(a.w);
  v[4] = (short)f2bf(b.x); v[5] = (short)f2bf(b.y);
  v[6] = (short)f2bf(b.z); v[7] = (short)f2bf(b.w);
  *(short8*)(word + (size_t)row * 512 + col) = v;
}

// ---------------- Leaf: h = (1 - sigm(word@Wz + bz)) * tanh(word@Wh + bh)
__global__ __launch_bounds__(256) void leaf_fused(
    const u16* __restrict__ word, const u16* __restrict__ BLT,
    const float* __restrict__ bz, const float* __restrict__ bh,
    u16* __restrict__ hout)   // 32768 x 1024 bf16
{
  __shared__ u16 sA [BM * BK];
  __shared__ u16 sBz[BN * BK];
  __shared__ u16 sBh[BN * BK];
  const int tid  = threadIdx.x;
  int bx, by; swz(blockIdx.x, 8, 256, bx, by);
  const int m0   = by * BM;
  const int n0   = bx * BN;
  const int lane = tid & 63;
  const int wave = tid >> 6;
  const int wm   = (wave >> 1) * 64;
  const int wn   = (wave & 1) * 64;
  const int lr   = lane & 15;
  const int q4   = lane >> 4;
  const int qd   = q4 * 4;
  const int xs   = lr & 7;
  const int srow = lane >> 3;
  const int sc   = lane & 7;
  const int goff = (sc ^ srow) * 8;

  const u16* aP [4]; const u16* bzP[4]; const u16* bhP[4];
  #pragma unroll
  for (int t = 0; t < 4; ++t) {
    const int row = (wave * 4 + t) * 8 + srow;
    aP [t] = word + (size_t)(m0 + row) * 512 + goff;
    bzP[t] = BLT  + (size_t)(n0 + row) * 512 + goff;
    bhP[t] = BLT  + (size_t)(1024 + n0 + row) * 512 + goff;
  }

  floatx4 accz[4][4], acch[4][4];
  #pragma unroll
  for (int j = 0; j < 4; ++j)
    #pragma unroll
    for (int i = 0; i < 4; ++i) {
      accz[j][i] = (floatx4){0.f, 0.f, 0.f, 0.f};
      acch[j][i] = (floatx4){0.f, 0.f, 0.f, 0.f};
    }

  for (int kt = 0; kt < 512 / BK; ++kt) {
    #pragma unroll
    for (int t = 0; t < 4; ++t) {
      const int slab = wave * 4 + t;
      ld_g2l16(aP [t], &sA [slab * 512]);
      ld_g2l16(bzP[t], &sBz[slab * 512]);
      ld_g2l16(bhP[t], &sBh[slab * 512]);
      aP[t] += BK; bzP[t] += BK; bhP[t] += BK;
    }
    __syncthreads();
    #pragma unroll
    for (int s = 0; s < 2; ++s) {
      const int ck = ((s * 4 + q4) ^ xs) * 8;
      short8 af[4], bz8[4], bh8[4];
      #pragma unroll
      for (int i = 0; i < 4; ++i)
        af[i] = *(const short8*)(&sA[(wm + i * 16 + lr) * BK + ck]);
      #pragma unroll
      for (int j = 0; j < 4; ++j) {
        bz8[j] = *(const short8*)(&sBz[(wn + j * 16 + lr) * BK + ck]);
        bh8[j] = *(const short8*)(&sBh[(wn + j * 16 + lr) * BK + ck]);
      }
      #pragma unroll
      for (int j = 0; j < 4; ++j)
        #pragma unroll
        for (int i = 0; i < 4; ++i) {
          accz[j][i] = __builtin_amdgcn_mfma_f32_16x16x32_bf16(bz8[j], af[i], accz[j][i], 0, 0, 0);
          acch[j][i] = __builtin_amdgcn_mfma_f32_16x16x32_bf16(bh8[j], af[i], acch[j][i], 0, 0, 0);
        }
    }
    __syncthreads();
  }

  #pragma unroll
  for (int j = 0; j < 4; ++j) {
    const int cb = n0 + wn + j * 16 + qd;
    const float4 bz4 = *(const float4*)(bz + cb);
    const float4 bh4 = *(const float4*)(bh + cb);
    #pragma unroll
    for (int i = 0; i < 4; ++i) {
      const int grow = m0 + wm + i * 16 + lr;
      short4v o;
      #pragma unroll
      for (int r = 0; r < 4; ++r) {
        const float z  = sigm(accz[j][i][r] + ((const float*)&bz4)[r]);
        const float ht = ftanh(acch[j][i][r] + ((const float*)&bh4)[r]);
        o[r] = (short)f2bf((1.f - z) * ht);
      }
      *(short4v*)(hout + (size_t)grow * 1024 + cb) = o;
    }
  }
}

// ---------------- Big-level GEMM (levels 0-2): C = A @ BT^T, fused epilogues.
__global__ __launch_bounds__(256) void gemm_fused(
    const u16* __restrict__ A, const u16* __restrict__ BT,
    int M, int K, int NX, int NY, int mode,
    const float* __restrict__ bias_z, const float* __restrict__ bias_r,
    const float* __restrict__ bias_h,
    const u16* __restrict__ hin2, const u16* __restrict__ zin,
    u16* __restrict__ out0, u16* __restrict__ out1, float* __restrict__ outf)
{
  __shared__ u16 sA[BM * BK];
  __shared__ u16 sB[BN * BK];
  const int tid  = threadIdx.x;
  int bx, by; swz(blockIdx.x, NX, NY, bx, by);
  const int m0   = by * BM;
  const int n0   = bx * BN;
  const int lane = tid & 63;
  const int wave = tid >> 6;
  const int wm   = (wave >> 1) * 64;
  const int wn   = (wave & 1) * 64;
  const int lr   = lane & 15;
  const int q4   = lane >> 4;
  const int qd   = q4 * 4;
  const int xs   = lr & 7;
  const int srow = lane >> 3;
  const int sc   = lane & 7;
  const int goff = (sc ^ srow) * 8;

  const u16* aP[4]; const u16* bP[4];
  #pragma unroll
  for (int t = 0; t < 4; ++t) {
    const int row = (wave * 4 + t) * 8 + srow;
    aP[t] = A  + (size_t)(m0 + row) * K + goff;
    bP[t] = BT + (size_t)(n0 + row) * K + goff;
  }

  floatx4 acc[4][4];
  #pragma unroll
  for (int j = 0; j < 4; ++j)
    #pragma unroll
    for (int i = 0; i < 4; ++i)
      acc[j][i] = (floatx4){0.f, 0.f, 0.f, 0.f};

  const int ksteps = K / BK;
  for (int kt = 0; kt < ksteps; ++kt) {
    #pragma unroll
    for (int t = 0; t < 4; ++t) {
      const int slab = wave * 4 + t;
      ld_g2l16(aP[t], &sA[slab * 512]);
      ld_g2l16(bP[t], &sB[slab * 512]);
      aP[t] += BK; bP[t] += BK;
    }
    __syncthreads();
    #pragma unroll
    for (int s = 0; s < 2; ++s) {
      const int ck = ((s * 4 + q4) ^ xs) * 8;
      short8 af[4], bfr[4];
      #pragma unroll
      for (int i = 0; i < 4; ++i)
        af[i] = *(const short8*)(&sA[(wm + i * 16 + lr) * BK + ck]);
      #pragma unroll
      for (int j = 0; j < 4; ++j)
        bfr[j] = *(const short8*)(&sB[(wn + j * 16 + lr) * BK + ck]);
      #pragma unroll
      for (int j = 0; j < 4; ++j)
        #pragma unroll
        for (int i = 0; i < 4; ++i)
          acc[j][i] = __builtin_amdgcn_mfma_f32_16x16x32_bf16(bfr[j], af[i], acc[j][i], 0, 0, 0);
    }
    __syncthreads();
  }

  #pragma unroll
  for (int j = 0; j < 4; ++j) {
    const int cb = n0 + wn + j * 16 + qd;
    if (mode == MODE_ZR) {
      if (cb < 1024) {
        const float4 b4 = *(const float4*)(bias_z + cb);
        #pragma unroll
        for (int i = 0; i < 4; ++i) {
          const int grow = m0 + wm + i * 16 + lr;
          if (grow >= M) continue;
          short4v o;
          #pragma unroll
          for (int r = 0; r < 4; ++r)
            o[r] = (short)f2bf(sigm(acc[j][i][r] + ((const float*)&b4)[r]));
          *(short4v*)(out0 + (size_t)grow * 1024 + cb) = o;
        }
      } else {
        const int c2 = cb - 1024;
        const float4 b4 = *(const float4*)(bias_r + c2);
        #pragma unroll
        for (int i = 0; i < 4; ++i) {
          const int grow = m0 + wm + i * 16 + lr;
          if (grow >= M) continue;
          const short4v hl4 = *(const short4v*)(hin2 + (size_t)grow * 2048 + c2);
          const short4v hr4 = *(const short4v*)(hin2 + (size_t)grow * 2048 + 1024 + c2);
          short4v ol, orr;
          #pragma unroll
          for (int r = 0; r < 4; ++r) {
            const float rv = sigm(acc[j][i][r] + ((const float*)&b4)[r]);
            ol[r]  = (short)f2bf(rv * bf2f((u16)hl4[r]));
            orr[r] = (short)f2bf(rv * bf2f((u16)hr4[r]));
          }
          *(short4v*)(out1 + (size_t)grow * 2048 + c2)        = ol;
          *(short4v*)(out1 + (size_t)grow * 2048 + 1024 + c2) = orr;
        }
      }
    } else { // MODE_OUT
      const float4 b4 = *(const float4*)(bias_h + cb);
      #pragma unroll
      for (int i = 0; i < 4; ++i) {
        const int grow = m0 + wm + i * 16 + lr;
        if (grow >= M) continue;
        const short4v z4  = *(const short4v*)(zin  + (size_t)grow * 1024 + cb);
        const short4v hl4 = *(const short4v*)(hin2 + (size_t)grow * 2048 + cb);
        const short4v hr4 = *(const short4v*)(hin2 + (size_t)grow * 2048 + 1024 + cb);
        float h[4];
        #pragma unroll
        for (int r = 0; r < 4; ++r) {
          const float ht = ftanh(acc[j][i][r] + ((const float*)&b4)[r]);
          const float z  = bf2f((u16)z4[r]);
          h[r] = z * (bf2f((u16)hl4[r]) + bf2f((u16)hr4[r])) + (1.f - z) * ht;
        }
        if (outf) {
          *(float4*)(outf + (size_t)grow * 1024 + cb) = (float4){h[0], h[1], h[2], h[3]};
        } else {
          short4v o;
          #pragma unroll
          for (int r = 0; r < 4; ++r) o[r] = (short)f2bf(h[r]);
          *(short4v*)(out0 + (size_t)grow * 1024 + cb) = o;
        }
      }
    }
  }
}

// ---------------- Split-K phase 1 (levels 3-8): partial GEMM over a K/S slice,
// bf16 partials to pbuf[sp] via plain stores (NO atomics; R10 proved numerics,
// R9 proved the two-phase dispatch-boundary mechanism).
__global__ __launch_bounds__(256) void gemm_pk(
    const u16* __restrict__ A, const u16* __restrict__ BT,
    int K, int TX, int S, int Mr,
    u16* __restrict__ pbuf)
{
  __shared__ u16 sA[BM * BK];
  __shared__ u16 sB[BN * BK];
  const int tid  = threadIdx.x;
  const int blk  = blockIdx.x;
  const int sp   = blk % S;
  const int tile = blk / S;
  const int bx   = tile % TX;
  const int by   = tile / TX;
  const int N    = TX * 128;
  const int m0   = by * BM;
  const int n0   = bx * BN;
  const int k0   = sp * (K / S);
  const int lane = tid & 63;
  const int wave = tid >> 6;
  const int wm   = (wave >> 1) * 64;
  const int wn   = (wave & 1) * 64;
  const int lr   = lane & 15;
  const int q4   = lane >> 4;
  const int qd   = q4 * 4;
  const int xs   = lr & 7;
  const int srow = lane >> 3;
  const int sc   = lane & 7;
  const int goff = (sc ^ srow) * 8;

  const u16* aP[4]; const u16* bP[4];
  #pragma unroll
  for (int t = 0; t < 4; ++t) {
    const int row = (wave * 4 + t) * 8 + srow;
    aP[t] = A  + (size_t)(m0 + row) * K + k0 + goff;  // OOB rows: in-ws garbage, masked in reduce
    bP[t] = BT + (size_t)(n0 + row) * K + k0 + goff;
  }

  floatx4 acc[4][4];
  #pragma unroll
  for (int j = 0; j < 4; ++j)
    #pragma unroll
    for (int i = 0; i < 4; ++i)
      acc[j][i] = (floatx4){0.f, 0.f, 0.f, 0.f};

  const int ksteps = (K / S) / BK;
  for (int kt = 0; kt < ksteps; ++kt) {
    #pragma unroll
    for (int t = 0; t < 4; ++t) {
      const int slab = wave * 4 + t;
      ld_g2l16(aP[t], &sA[slab * 512]);
      ld_g2l16(bP[t], &sB[slab * 512]);
      aP[t] += BK; bP[t] += BK;
    }
    __syncthreads();
    #pragma unroll
    for (int s = 0; s < 2; ++s) {
      const int ck = ((s * 4 + q4) ^ xs) * 8;
      short8 af[4], bfr[4];
      #pragma unroll
      for (int i = 0; i < 4; ++i)
        af[i] = *(const short8*)(&sA[(wm + i * 16 + lr) * BK + ck]);
      #pragma unroll
      for (int j = 0; j < 4; ++j)
        bfr[j] = *(const short8*)(&sB[(wn + j * 16 + lr) * BK + ck]);
      #pragma unroll
      for (int j = 0; j < 4; ++j)
        #pragma unroll
        for (int i = 0; i < 4; ++i)
          acc[j][i] = __builtin_amdgcn_mfma_f32_16x16x32_bf16(bfr[j], af[i], acc[j][i], 0, 0, 0);
    }
    __syncthreads();
  }

  u16* base = pbuf + (size_t)sp * Mr * N;
  #pragma unroll
  for (int j = 0; j < 4; ++j) {
    const int cb = n0 + wn + j * 16 + qd;
    #pragma unroll
    for (int i = 0; i < 4; ++i) {
      const int grow = m0 + wm + i * 16 + lr;
      short4v o;
      #pragma unroll
      for (int r = 0; r < 4; ++r) o[r] = (short)f2bf(acc[j][i][r]);
      *(short4v*)(base + (size_t)grow * N + cb) = o;
    }
  }
}

// ---------------- Split-K phase 2: sum S bf16 slices + ZR epilogue (N=2048)
__global__ __launch_bounds__(256) void reduce_zr(
    const u16* __restrict__ pbuf, int M, int Mr, int S,
    const float* __restrict__ bias_z, const float* __restrict__ bias_r,
    const u16* __restrict__ hin2,
    u16* __restrict__ out0, u16* __restrict__ out1)
{
  const int t = blockIdx.x * 256 + threadIdx.x;
  const int grow = t >> 9;
  const int cb = (t & 511) * 4;
  if (grow >= M) return;
  float v[4] = {0.f, 0.f, 0.f, 0.f};
  for (int s = 0; s < S; ++s) {
    const short4v p = *(const short4v*)(pbuf + ((size_t)s * Mr + grow) * 2048 + cb);
    #pragma unroll
    for (int r = 0; r < 4; ++r) v[r] += bf2f((u16)p[r]);
  }
  if (cb < 1024) {
    short4v o;
    #pragma unroll
    for (int r = 0; r < 4; ++r)
      o[r] = (short)f2bf(sigm(v[r] + bias_z[cb + r]));
    *(short4v*)(out0 + (size_t)grow * 1024 + cb) = o;
  } else {
    const int c2 = cb - 1024;
    const short4v hl4 = *(const short4v*)(hin2 + (size_t)grow * 2048 + c2);
    const short4v hr4 = *(const short4v*)(hin2 + (size_t)grow * 2048 + 1024 + c2);
    short4v ol, orr;
    #pragma unroll
    for (int r = 0; r < 4; ++r) {
      const float rv = sigm(v[r] + bias_r[c2 + r]);
      ol[r]  = (short)f2bf(rv * bf2f((u16)hl4[r]));
      orr[r] = (short)f2bf(rv * bf2f((u16)hr4[r]));
    }
    *(short4v*)(out1 + (size_t)grow * 2048 + c2)        = ol;
    *(short4v*)(out1 + (size_t)grow * 2048 + 1024 + c2) = orr;
  }
}

// ---------------- Split-K phase 2: sum S bf16 slices + OUT epilogue (N=1024)
__global__ __launch_bounds__(256) void reduce_out(
    const u16* __restrict__ pbuf, int M, int Mr, int S,
    const float* __restrict__ bias_h,
    const u16* __restrict__ hin2, const u16* __restrict__ zin,
    u16* __restrict__ out0, float* __restrict__ outf)
{
  const int t = blockIdx.x * 256 + threadIdx.x;
  const int grow = t >> 8;
  const int cb = (t & 255) * 4;
  if (grow >= M) return;
  float v[4] = {0.f, 0.f, 0.f, 0.f};
  for (int s = 0; s < S; ++s) {
    const short4v p = *(const short4v*)(pbuf + ((size_t)s * Mr + grow) * 1024 + cb);
    #pragma unroll
    for (int r = 0; r < 4; ++r) v[r] += bf2f((u16)p[r]);
  }
  const short4v z4  = *(const short4v*)(zin  + (size_t)grow * 1024 + cb);
  const short4v hl4 = *(const short4v*)(hin2 + (size_t)grow * 2048 + cb);
  const short4v hr4 = *(const short4v*)(hin2 + (size_t)grow * 2048 + 1024 + cb);
  float h[4];
  #pragma unroll
  for (int r = 0; r < 4; ++r) {
    const float ht = ftanh(v[r] + bias_h[cb + r]);
    const float z  = bf2f((u16)z4[r]);
    h[r] = z * (bf2f((u16)hl4[r]) + bf2f((u16)hr4[r])) + (1.f - z) * ht;
  }
  if (outf) {
    *(float4*)(outf + (size_t)grow * 1024 + cb) = (float4){h[0], h[1], h[2], h[3]};
  } else {
    short4v o;
    #pragma unroll
    for (int r = 0; r < 4; ++r) o[r] = (short)f2bf(h[r]);
    *(short4v*)(out0 + (size_t)grow * 1024 + cb) = o;
  }
}

// ---------------- fused weight/bias packing (f32 -> bf16 B^T stacks), 1 dispatch
__global__ __launch_bounds__(256) void pack_all(
    const float* __restrict__ Uzl, const float* __restrict__ Uzr,
    const float* __restrict__ Url, const float* __restrict__ Urr,
    const float* __restrict__ Uhl, const float* __restrict__ Uhr,
    const float* __restrict__ Wz,  const float* __restrict__ Wh,
    const float* bz0, const float* bz1, const float* bz2,
    const float* br0, const float* br1, const float* br2,
    const float* bh0, const float* bh1, const float* bh2,
    u16* __restrict__ B1T, u16* __restrict__ B2T, u16* __restrict__ BLT,
    float* __restrict__ bz, float* __restrict__ br, float* __restrict__ bh)
{
  int t = blockIdx.x * 256 + threadIdx.x;
  if (t < 2048 * 2048) {                       // B1T
    const int n = t >> 11, k = t & 2047;
    const float* src = (n < 1024) ? ((k < 1024) ? Uzl : Uzr)
                                  : ((k < 1024) ? Url : Urr);
    B1T[t] = f2bf(src[(size_t)(k & 1023) * 1024 + (n & 1023)]);
    return;
  }
  t -= 2048 * 2048;
  if (t < 1024 * 2048) {                       // B2T
    const int n = t >> 11, k = t & 2047;
    const float* src = (k < 1024) ? Uhl : Uhr;
    B2T[t] = f2bf(src[(size_t)(k & 1023) * 1024 + n]);
    return;
  }
  t -= 1024 * 2048;
  if (t < 2048 * 512) {                        // BLT
    const int n = t >> 9, k = t & 511;
    const float* src = (n < 1024) ? Wz : Wh;
    BLT[t] = f2bf(src[(size_t)k * 1024 + (n & 1023)]);
    return;
  }
  t -= 2048 * 512;
  if (t < 1024) {                              // biases
    bz[t] = bz0[t] + bz1[t] + bz2[t];
    br[t] = br0[t] + br1[t] + br2[t];
    bh[t] = bh0[t] + bh1[t] + bh2[t];
  }
}

extern "C" void kernel_launch(void* const* d_in, const int* in_sizes, int n_in,
                              void* d_out, int out_size, void* d_ws, size_t ws_size,
                              hipStream_t stream)
{
  const int*   tokens = (const int*)d_in[0];
  const float* emb  = (const float*)d_in[1];
  const float* W_z  = (const float*)d_in[2];
  const float* b_z  = (const float*)d_in[3];
  const float* U_zl = (const float*)d_in[4];
  const float* b_zl = (const float*)d_in[5];
  const float* U_zr = (const float*)d_in[6];
  const float* b_zr = (const float*)d_in[7];
  // d_in[8] = W_r: provably unused (leaf r multiplies zero state)
  const float* b_r  = (const float*)d_in[9];
  const float* U_rl = (const float*)d_in[10];
  const float* b_rl = (const float*)d_in[11];
  const float* U_rr = (const float*)d_in[12];
  const float* b_rr = (const float*)d_in[13];
  const float* W_h  = (const float*)d_in[14];
  const float* b_h  = (const float*)d_in[15];
  const float* U_hl = (const float*)d_in[16];
  const float* b_hl = (const float*)d_in[17];
  const float* U_hr = (const float*)d_in[18];
  const float* b_hr = (const float*)d_in[19];

  char* ws = (char*)d_ws;
  size_t off = 0;
  auto alloc = [&](size_t bytes) -> char* {
    char* p = ws + off; off += (bytes + 255) & ~(size_t)255; return p;
  };
  u16*   B1T  = (u16*)alloc((size_t)2048 * 2048 * 2);   //  8 MB
  u16*   B2T  = (u16*)alloc((size_t)1024 * 2048 * 2);   //  4 MB
  u16*   BLT  = (u16*)alloc((size_t)2048 * 512 * 2);    //  2 MB
  float* bz   = (float*)alloc(1024 * 4);
  float* br   = (float*)alloc(1024 * 4);
  float* bh   = (float*)alloc(1024 * 4);
  u16*   wrd  = (u16*)alloc((size_t)32768 * 512 * 2);   // 32 MB (dead after leaf -> pbuf)
  u16*   hA   = (u16*)alloc((size_t)32768 * 1024 * 2);  // 64 MB
  u16*   hB   = (u16*)alloc((size_t)16384 * 1024 * 2);  // 32 MB
  u16*   zbuf = (u16*)alloc((size_t)16384 * 1024 * 2);  // 32 MB
  u16*   rlrr = (u16*)alloc((size_t)16384 * 2048 * 2);  // 64 MB
  u16*   pbuf = wrd;                                    // aliases wrd (max 32 MB bf16)
  (void)ws_size; (void)in_sizes; (void)n_in; (void)out_size;

  pack_all<<<dim3((2048*2048 + 1024*2048 + 2048*512 + 1024 + 255) / 256),
             dim3(256), 0, stream>>>(
      U_zl, U_zr, U_rl, U_rr, U_hl, U_hr, W_z, W_h,
      b_z, b_zl, b_zr, b_r, b_rl, b_rr, b_h, b_hl, b_hr,
      B1T, B2T, BLT, bz, br, bh);

  gather_word<<<dim3(8192), dim3(256), 0, stream>>>(tokens, emb, wrd);
  leaf_fused<<<dim3(8 * 256), dim3(256), 0, stream>>>(wrd, BLT, bz, bh, hA);

  // 9 halving levels; h (2R x 1024) viewed as (R x 2048) = [hl|hr]
  const u16* hin = hA;
  u16* hout = hB;
  int nodes = 32768;
  for (int lvl = 0; lvl < 9; ++lvl) {
    const int R = nodes >> 1;
    float* outf = (lvl == 8) ? (float*)d_out : nullptr;
    if (lvl < 3) {
      const int NY = (R + 127) / 128;
      gemm_fused<<<dim3(16 * NY), dim3(256), 0, stream>>>(
          hin, B1T, R, 2048, 16, NY, MODE_ZR,
          bz, br, bh, hin, nullptr, zbuf, rlrr, nullptr);
      gemm_fused<<<dim3(8 * NY), dim3(256), 0, stream>>>(
          rlrr, B2T, R, 2048, 8, NY, MODE_OUT,
          bz, br, bh, hin, zbuf, hout, nullptr, outf);
    } else {
      const int TY = (R + 127) / 128;
      const int Mr = TY * 128;
      const int S  = (R >= 1024) ? 4 : (R >= 256) ? 8 : 16;
      // pbuf (bf16): ZR = S*Mr*2048*2 <= 32 MB for all levels 3-8
      gemm_pk<<<dim3(16 * TY * S), dim3(256), 0, stream>>>(
          hin, B1T, 2048, 16, S, Mr, pbuf);
      reduce_zr<<<dim3(R * 2), dim3(256), 0, stream>>>(
          pbuf, R, Mr, S, bz, br, hin, zbuf, rlrr);
      // OUT: N=1024
      gemm_pk<<<dim3(8 * TY * S), dim3(256), 0, stream>>>(
          rlrr, B2T, 2048, 8, S, Mr, pbuf);
      reduce_out<<<dim3(R), dim3(256), 0, stream>>>(
          pbuf, R, Mr, S, bh, hin, zbuf, hout, outf);
    }
    u16* tmp = (u16*)hin; hin = hout; hout = tmp;
    nodes = R;
  }
}